// Round 14
// baseline (486.079 us; speedup 1.0000x reference)
//
#include <hip/hip_runtime.h>
#include <hip/hip_bf16.h>

#define NN 8192
#define FIN 256
#define FOUT 64
#define L2E 1.4426950408889634f
#define PADK 40   // LDS k-stride in shorts (32 data + 8 pad -> even bank spread)

typedef __attribute__((ext_vector_type(8))) short short8;
typedef __attribute__((ext_vector_type(4))) float f32x4;
typedef __attribute__((ext_vector_type(4))) int   iv4;

// Barrier with LDS-only drain: leaves vmcnt (global prefetch) in flight.
#define BAR() do { \
  __asm__ __volatile__("s_waitcnt lgkmcnt(0)" ::: "memory"); \
  __builtin_amdgcn_s_barrier(); \
  __asm__ __volatile__("" ::: "memory"); \
} while (0)

__device__ __forceinline__ unsigned short f2bf(float x){
  unsigned u = __float_as_uint(x);
  u += 0x7FFFu + ((u >> 16) & 1u);      // RTNE
  return (unsigned short)(u >> 16);
}

// spread4: deposit bit i of 8-bit x at bit 4i.
__device__ __forceinline__ unsigned spread4(unsigned x){
  x &= 0xFFu;
  x = (x | (x << 12)) & 0x000F000Fu;
  x = (x | (x << 6))  & 0x03030303u;
  x = (x | (x << 3))  & 0x11111111u;
  return x;
}

// Convert one 1-KB group (256 j, lane l holds j = g*256 + 4l + c) to 8 mask
// words (j-order bits, layout validated R12/R13). Lanes 0-7 store (32-B store).
__device__ __forceinline__ void cv_process(iv4 d, int l,
                                           unsigned* __restrict__ mp, int g){
  unsigned n = (unsigned)(d.x != 0)        | ((unsigned)(d.y != 0) << 1)
             | ((unsigned)(d.z != 0) << 2) | ((unsigned)(d.w != 0) << 3);
  unsigned long long B0 = __ballot((n & 1u) != 0);   // bit l <-> j = 4l+0
  unsigned long long B1 = __ballot((n & 2u) != 0);   // j = 4l+1
  unsigned long long B2 = __ballot((n & 4u) != 0);   // j = 4l+2
  unsigned long long B3 = __ballot((n & 8u) != 0);   // j = 4l+3
  const int hi = l & 4, sh = (l & 3) * 8;            // byte (l&7) of each u64
  unsigned b0 = (unsigned)((hi ? (B0 >> 32) : B0) >> sh);
  unsigned b1 = (unsigned)((hi ? (B1 >> 32) : B1) >> sh);
  unsigned b2 = (unsigned)((hi ? (B2 >> 32) : B2) >> sh);
  unsigned b3 = (unsigned)((hi ? (B3 >> 32) : B3) >> sh);
  unsigned word = spread4(b0) | (spread4(b1) << 1)
                | (spread4(b2) << 2) | (spread4(b3) << 3);
  if (l < 8) mp[g*8 + l] = word;   // word w covers j [g*256+w*32, +32)
}

// ---- k_pm: fused prep + adj->bitmask converter, bid&1 interleave.
// R14: converter wave = TWO independent rows, 16 iv4 loads in flight
// (2 streams x 8-deep). R13's single 8-deep stream hit ~2.5 TB/s — theory:
// per-wave vmcnt window caps issue rate; doubling outstanding bytes/wave
// should ~halve converter time. Everything else byte-identical to R13.
__global__ __launch_bounds__(256) void k_pm(const float* __restrict__ h,
    const float* __restrict__ W, const float* __restrict__ a,
    const int* __restrict__ adj, unsigned short* __restrict__ WhT,
    float* __restrict__ fs, float* __restrict__ fd,
    unsigned* __restrict__ gmax_u, unsigned* __restrict__ mask){
  const int bid = blockIdx.x, t = threadIdx.x;
  const int l = t & 63, wv = t >> 6;
  if ((bid & 1) == 0){
    const int pid = bid >> 1;               // 0..1023
    __shared__ float Ws[128*64];   // 32 KB: half of W (k-tiled)
    __shared__ float hs[8][128];
    const int rb = pid * 8;                 // 8 rows per block, 2 per wave
    float acc0 = 0.f, acc1 = 0.f;
    for (int half = 0; half < 2; ++half){
      if (half) __syncthreads();
      for (int i = t; i < 2048; i += 256)
        ((float4*)Ws)[i] = ((const float4*)W)[half*2048 + i];
      {
        int rr = t >> 5, cc = t & 31;
        ((float4*)&hs[rr][0])[cc] =
            *(const float4*)(h + (size_t)(rb+rr)*FIN + half*128 + cc*4);
      }
      __syncthreads();
      #pragma unroll 8
      for (int k = 0; k < 128; ++k){
        float wval = Ws[k*64 + l];           // lane l = output feature
        acc0 = fmaf(hs[wv*2+0][k], wval, acc0);
        acc1 = fmaf(hs[wv*2+1][k], wval, acc1);
      }
    }
    const int r0 = rb + wv*2, r1 = r0 + 1;
    float a1 = a[l], a2 = a[64 + l];
    float p0 = acc0*a1, q0 = acc0*a2, p1 = acc1*a1, q1 = acc1*a2;
    #pragma unroll
    for (int m = 1; m < 64; m <<= 1){
      p0 += __shfl_xor(p0, m); q0 += __shfl_xor(q0, m);
      p1 += __shfl_xor(p1, m); q1 += __shfl_xor(q1, m);
    }
    if (l == 0){
      fs[r0] = p0*L2E; fs[r1] = p1*L2E; fd[r0] = q0*L2E; fd[r1] = q1*L2E;
      atomicMax(gmax_u, __float_as_uint(q0*L2E + 64.0f));
      atomicMax(gmax_u, __float_as_uint(q1*L2E + 64.0f));
    }
    WhT[(size_t)l*NN + r0] = f2bf(acc0);
    WhT[(size_t)l*NN + r1] = f2bf(acc1);
  } else {
    const int cid = bid >> 1;               // 0..1023
    const unsigned r0 = (unsigned)cid*8u + (unsigned)wv*2u;   // 2 rows per wave
    const unsigned r1 = r0 + 1u;
    const iv4* __restrict__ apA = (const iv4*)(adj + (size_t)r0*8192u) + l;
    const iv4* __restrict__ apB = (const iv4*)(adj + (size_t)r1*8192u) + l;
    unsigned* __restrict__ mpA = mask + r0*256u;
    unsigned* __restrict__ mpB = mask + r1*256u;
    // 2 streams x 8 x 1-KB loads in flight = 16 KB/wave outstanding
    iv4 a0 = apA[0*64], a1 = apA[1*64], a2 = apA[2*64], a3 = apA[3*64];
    iv4 a4 = apA[4*64], a5 = apA[5*64], a6 = apA[6*64], a7 = apA[7*64];
    iv4 b0 = apB[0*64], b1 = apB[1*64], b2 = apB[2*64], b3 = apB[3*64];
    iv4 b4 = apB[4*64], b5 = apB[5*64], b6 = apB[6*64], b7 = apB[7*64];
    #pragma unroll 1
    for (int i = 0; i < 32; i += 8){
      cv_process(a0, l, mpA, i+0); if (i+ 8 < 32) a0 = apA[(i+ 8)*64];
      cv_process(b0, l, mpB, i+0); if (i+ 8 < 32) b0 = apB[(i+ 8)*64];
      cv_process(a1, l, mpA, i+1); if (i+ 9 < 32) a1 = apA[(i+ 9)*64];
      cv_process(b1, l, mpB, i+1); if (i+ 9 < 32) b1 = apB[(i+ 9)*64];
      cv_process(a2, l, mpA, i+2); if (i+10 < 32) a2 = apA[(i+10)*64];
      cv_process(b2, l, mpB, i+2); if (i+10 < 32) b2 = apB[(i+10)*64];
      cv_process(a3, l, mpA, i+3); if (i+11 < 32) a3 = apA[(i+11)*64];
      cv_process(b3, l, mpB, i+3); if (i+11 < 32) b3 = apB[(i+11)*64];
      cv_process(a4, l, mpA, i+4); if (i+12 < 32) a4 = apA[(i+12)*64];
      cv_process(b4, l, mpB, i+4); if (i+12 < 32) b4 = apB[(i+12)*64];
      cv_process(a5, l, mpA, i+5); if (i+13 < 32) a5 = apA[(i+13)*64];
      cv_process(b5, l, mpB, i+5); if (i+13 < 32) b5 = apB[(i+13)*64];
      cv_process(a6, l, mpA, i+6); if (i+14 < 32) a6 = apA[(i+14)*64];
      cv_process(b6, l, mpB, i+6); if (i+14 < 32) b6 = apB[(i+14)*64];
      cv_process(a7, l, mpA, i+7); if (i+15 < 32) a7 = apA[(i+15)*64];
      cv_process(b7, l, mpB, i+7); if (i+15 < 32) b7 = apB[(i+15)*64];
    }
  }
}

// ---- k_attn (R10/R12-verified, unchanged): block = 64 i-rows x 1024-j kchunk.
// WhT+fd staged in LDS; adj via bitmask (1 word / 32 j, L2-resident).
__device__ __forceinline__ void attn_math(unsigned mbits, f32x4 fv0, f32x4 fv1,
    short8 w0, short8 w1, short8 w2, short8 w3,
    float fsrL, float mL, f32x4* acc, float& s0, float& s1){
  const float fv[8] = {fv0[0],fv0[1],fv0[2],fv0[3], fv1[0],fv1[1],fv1[2],fv1[3]};
  float w[8];
  #pragma unroll
  for (int j = 0; j < 8; ++j){
    float x  = fsrL + fv[j];                      // log2 domain
    float tt = fmaxf(x, 0.2f*x);                  // leaky_relu (scale-invariant)
    float e  = __builtin_amdgcn_exp2f(tt - mL);   // v_exp_f32
    w[j] = (mbits & (1u << j)) ? e : 0.0f;        // adj bit
  }
  s0 += (w[0]+w[2]) + (w[4]+w[6]);
  s1 += (w[1]+w[3]) + (w[5]+w[7]);
  short8 af;
  __hip_bfloat162* afp = (__hip_bfloat162*)&af;
  #pragma unroll
  for (int j = 0; j < 4; ++j)
    afp[j] = __float22bfloat162_rn(make_float2(w[2*j], w[2*j+1]));  // v_cvt_pk_bf16_f32
  acc[0] = __builtin_amdgcn_mfma_f32_16x16x32_bf16(af, w0, acc[0], 0,0,0);
  acc[1] = __builtin_amdgcn_mfma_f32_16x16x32_bf16(af, w1, acc[1], 0,0,0);
  acc[2] = __builtin_amdgcn_mfma_f32_16x16x32_bf16(af, w2, acc[2], 0,0,0);
  acc[3] = __builtin_amdgcn_mfma_f32_16x16x32_bf16(af, w3, acc[3], 0,0,0);
}

// Verified layouts (m89/m120): A[m=lane&15][k=(lane>>4)*8+j],
// B[k=(lane>>4)*8+j][n=lane&15], C col=lane&15 row=(lane>>4)*4+reg.
__global__ __launch_bounds__(256, 4) void k_attn(const unsigned* __restrict__ mask,
    const unsigned short* __restrict__ WhT, const float* __restrict__ fs,
    const float* __restrict__ fd, const unsigned* __restrict__ gmax_u,
    float* __restrict__ acc_out, float* __restrict__ s_out){
  __shared__ unsigned short bslab[2][64*PADK];   // [buf][n][k]
  __shared__ float fslab[2][32];
  const int t = threadIdx.x, l = t & 63, wv = t >> 6;
  const int g = blockIdx.x & 127;        // 128 groups of 64 i-rows
  const int kchunk = blockIdx.x >> 7;    // 8 k-splits of 1024 j
  const int row = l & 15, quad = l >> 4;
  const int ibase = g*64 + wv*16;
  const int irow  = ibase + row;
  const float gmaxL = __uint_as_float(*gmax_u) - 64.0f;
  const float fsrL  = fs[irow];
  const float xL    = fsrL + gmaxL;
  const float mL    = fmaxf(xL, 0.2f*xL);  // row-max upper bound (leaky monotone)

  const unsigned jbase = (unsigned)kchunk*1024u;
  const unsigned m_off = (unsigned)irow*256u + (jbase >> 5);  // word per 32 j
  const unsigned sg_off = (unsigned)l*8192u + jbase + (unsigned)wv*8u;
  const int      sl_off = l*PADK + wv*8;
  const int      qsh    = quad*8;

  f32x4 acc[4];
  #pragma unroll
  for (int nb = 0; nb < 4; ++nb) acc[nb] = (f32x4){0.f,0.f,0.f,0.f};

  // prologue: stage step 0 into buf 0; prefetch mask words for steps 0,1
  {
    short8 v = *(const short8*)(WhT + sg_off);
    *(short8*)&bslab[0][sl_off] = v;
    if (t < 32) fslab[0][t] = fd[jbase + t];
  }
  unsigned m0 = mask[m_off + 0] >> qsh;
  unsigned m1 = mask[m_off + 1] >> qsh;

  float s0 = 0.f, s1 = 0.f;
  short8 nw; float nf = 0.f;

  #pragma unroll 1
  for (int s = 0; s < 32; s += 2){
    // ---- even sub-step: consume buf0/m0, stage s+1 -> buf1
    BAR();
    nw = *(const short8*)(WhT + sg_off + (s+1)*32);
    if (t < 32) nf = fd[jbase + (s+1)*32 + t];
    {
      f32x4 fv0 = *(const f32x4*)&fslab[0][qsh];
      f32x4 fv1 = *(const f32x4*)&fslab[0][qsh + 4];
      short8 w0 = *(const short8*)&bslab[0][( 0 + row)*PADK + qsh];
      short8 w1 = *(const short8*)&bslab[0][(16 + row)*PADK + qsh];
      short8 w2 = *(const short8*)&bslab[0][(32 + row)*PADK + qsh];
      short8 w3 = *(const short8*)&bslab[0][(48 + row)*PADK + qsh];
      attn_math(m0, fv0, fv1, w0, w1, w2, w3, fsrL, mL, acc, s0, s1);
    }
    if (s + 2 < 32) m0 = mask[m_off + s + 2] >> qsh;
    *(short8*)&bslab[1][sl_off] = nw;
    if (t < 32) fslab[1][t] = nf;

    // ---- odd sub-step: consume buf1/m1, stage s+2 -> buf0
    BAR();
    if (s + 2 < 32){
      nw = *(const short8*)(WhT + sg_off + (s+2)*32);
      if (t < 32) nf = fd[jbase + (s+2)*32 + t];
    }
    {
      f32x4 fv0 = *(const f32x4*)&fslab[1][qsh];
      f32x4 fv1 = *(const f32x4*)&fslab[1][qsh + 4];
      short8 w0 = *(const short8*)&bslab[1][( 0 + row)*PADK + qsh];
      short8 w1 = *(const short8*)&bslab[1][(16 + row)*PADK + qsh];
      short8 w2 = *(const short8*)&bslab[1][(32 + row)*PADK + qsh];
      short8 w3 = *(const short8*)&bslab[1][(48 + row)*PADK + qsh];
      attn_math(m1, fv0, fv1, w0, w1, w2, w3, fsrL, mL, acc, s0, s1);
    }
    if (s + 3 < 32) m1 = mask[m_off + s + 3] >> qsh;
    if (s + 2 < 32){
      *(short8*)&bslab[0][sl_off] = nw;
      if (t < 32) fslab[0][t] = nf;
    }
  }

  float sacc = s0 + s1;
  sacc += __shfl_xor(sacc, 16);
  sacc += __shfl_xor(sacc, 32);
  if (l < 16) s_out[kchunk*NN + ibase + l] = sacc;
  float* op = acc_out + ((size_t)kchunk*NN + ibase)*FOUT;
  #pragma unroll
  for (int nb = 0; nb < 4; ++nb)
    #pragma unroll
    for (int r = 0; r < 4; ++r)
      op[(quad*4 + r)*FOUT + nb*16 + row] = acc[nb][r];
}

// ---- k_out: combine 8 split-K partials, normalize, ELU.
__global__ __launch_bounds__(256) void k_out(const float* __restrict__ acc,
    const float* __restrict__ s, float* __restrict__ out){
  const int idx = blockIdx.x*256 + threadIdx.x;   // 524288 total
  const int i = idx >> 6;
  float num = 0.f, den = 0.f;
  #pragma unroll
  for (int ks = 0; ks < 8; ++ks){
    num += acc[idx + (size_t)ks*(NN*FOUT)];
    den += s[i + ks*NN];
  }
  float x = num / den;
  out[idx] = (x > 0.f) ? x : (__expf(x) - 1.0f);
}

extern "C" void kernel_launch(void* const* d_in, const int* in_sizes, int n_in,
                              void* d_out, int out_size, void* d_ws, size_t ws_size,
                              hipStream_t stream){
  const float* h   = (const float*)d_in[0];
  const int*   adj = (const int*)d_in[1];
  const float* W   = (const float*)d_in[2];
  const float* a   = (const float*)d_in[3];
  char* ws = (char*)d_ws;
  // ws: [0,1M) WhT | 1M fs | +32K fd | +64K gmax | [2M,18M) acc x8 |
  //     [20M,+256K) s x8 | [48M,56M) mask (2M words)
  unsigned short* WhT = (unsigned short*)ws;
  float*    fs     = (float*)(ws + (1u<<20));
  float*    fd     = (float*)(ws + (1u<<20) + 32768);
  unsigned* gmax_u = (unsigned*)(ws + (1u<<20) + 65536);
  float*    acc    = (float*)(ws + (2u<<20));
  float*    s_ws   = (float*)(ws + (20u<<20));
  unsigned* mask   = (unsigned*)(ws + (48u<<20));

  (void)hipMemsetAsync(gmax_u, 0, 4, stream);
  k_pm<<<2048, 256, 0, stream>>>(h, W, a, adj, WhT, fs, fd, gmax_u, mask);
  k_attn<<<1024, 256, 0, stream>>>(mask, WhT, fs, fd, gmax_u, acc, s_ws);
  k_out<<<2048, 256, 0, stream>>>(acc, s_ws, (float*)d_out);
}

// Round 15
// 468.698 us; speedup vs baseline: 1.0371x; 1.0371x over previous
//
#include <hip/hip_runtime.h>
#include <hip/hip_bf16.h>

#define NN 8192
#define FIN 256
#define FOUT 64
#define L2E 1.4426950408889634f
#define PADK 40   // LDS k-stride in shorts (32 data + 8 pad -> even bank spread)

typedef __attribute__((ext_vector_type(8))) short short8;
typedef __attribute__((ext_vector_type(4))) float f32x4;
typedef __attribute__((ext_vector_type(4))) int   iv4;

// Barrier with LDS-only drain: leaves vmcnt (global prefetch) in flight.
#define BAR() do { \
  __asm__ __volatile__("s_waitcnt lgkmcnt(0)" ::: "memory"); \
  __builtin_amdgcn_s_barrier(); \
  __asm__ __volatile__("" ::: "memory"); \
} while (0)

__device__ __forceinline__ unsigned short f2bf(float x){
  unsigned u = __float_as_uint(x);
  u += 0x7FFFu + ((u >> 16) & 1u);      // RTNE
  return (unsigned short)(u >> 16);
}

// spread4: deposit bit i of 8-bit x at bit 4i.
__device__ __forceinline__ unsigned spread4(unsigned x){
  x &= 0xFFu;
  x = (x | (x << 12)) & 0x000F000Fu;
  x = (x | (x << 6))  & 0x03030303u;
  x = (x | (x << 3))  & 0x11111111u;
  return x;
}

// Convert one 1-KB group (256 j, lane l holds j = g*256 + 4l + c) to 8 mask
// words (j-order bits, layout validated R12/R13). Lanes 0-7 store (32-B store).
__device__ __forceinline__ void cv_process(iv4 d, int l,
                                           unsigned* __restrict__ mp, int g){
  unsigned n = (unsigned)(d.x != 0)        | ((unsigned)(d.y != 0) << 1)
             | ((unsigned)(d.z != 0) << 2) | ((unsigned)(d.w != 0) << 3);
  unsigned long long B0 = __ballot((n & 1u) != 0);   // bit l <-> j = 4l+0
  unsigned long long B1 = __ballot((n & 2u) != 0);   // j = 4l+1
  unsigned long long B2 = __ballot((n & 4u) != 0);   // j = 4l+2
  unsigned long long B3 = __ballot((n & 8u) != 0);   // j = 4l+3
  const int hi = l & 4, sh = (l & 3) * 8;            // byte (l&7) of each u64
  unsigned b0 = (unsigned)((hi ? (B0 >> 32) : B0) >> sh);
  unsigned b1 = (unsigned)((hi ? (B1 >> 32) : B1) >> sh);
  unsigned b2 = (unsigned)((hi ? (B2 >> 32) : B2) >> sh);
  unsigned b3 = (unsigned)((hi ? (B3 >> 32) : B3) >> sh);
  unsigned word = spread4(b0) | (spread4(b1) << 1)
                | (spread4(b2) << 2) | (spread4(b3) << 3);
  if (l < 8) mp[g*8 + l] = word;   // word w covers j [g*256+w*32, +32)
}

// ---- k_pm: fused prep + adj->bitmask converter, bid&1 interleave.
// R15 converter: GRID-STRIDE over quarter-rows (8 KB units) — all 1024 conv
// blocks march through adj in lockstep, keeping a dense ~8 MB chip-wide
// window (m13 copy-kernel shape). R9/R13 lesson: thousands of private
// per-wave row streams thrash DRAM; request *pattern* beats per-wave depth.
__global__ __launch_bounds__(256) void k_pm(const float* __restrict__ h,
    const float* __restrict__ W, const float* __restrict__ a,
    const int* __restrict__ adj, unsigned short* __restrict__ WhT,
    float* __restrict__ fs, float* __restrict__ fd,
    unsigned* __restrict__ gmax_u, unsigned* __restrict__ mask){
  const int bid = blockIdx.x, t = threadIdx.x;
  const int l = t & 63, wv = t >> 6;
  if ((bid & 1) == 0){
    const int pid = bid >> 1;               // 0..1023
    __shared__ float Ws[128*64];   // 32 KB: half of W (k-tiled)
    __shared__ float hs[8][128];
    const int rb = pid * 8;                 // 8 rows per block, 2 per wave
    float acc0 = 0.f, acc1 = 0.f;
    for (int half = 0; half < 2; ++half){
      if (half) __syncthreads();
      for (int i = t; i < 2048; i += 256)
        ((float4*)Ws)[i] = ((const float4*)W)[half*2048 + i];
      {
        int rr = t >> 5, cc = t & 31;
        ((float4*)&hs[rr][0])[cc] =
            *(const float4*)(h + (size_t)(rb+rr)*FIN + half*128 + cc*4);
      }
      __syncthreads();
      #pragma unroll 8
      for (int k = 0; k < 128; ++k){
        float wval = Ws[k*64 + l];           // lane l = output feature
        acc0 = fmaf(hs[wv*2+0][k], wval, acc0);
        acc1 = fmaf(hs[wv*2+1][k], wval, acc1);
      }
    }
    const int r0 = rb + wv*2, r1 = r0 + 1;
    float a1 = a[l], a2 = a[64 + l];
    float p0 = acc0*a1, q0 = acc0*a2, p1 = acc1*a1, q1 = acc1*a2;
    #pragma unroll
    for (int m = 1; m < 64; m <<= 1){
      p0 += __shfl_xor(p0, m); q0 += __shfl_xor(q0, m);
      p1 += __shfl_xor(p1, m); q1 += __shfl_xor(q1, m);
    }
    if (l == 0){
      fs[r0] = p0*L2E; fs[r1] = p1*L2E; fd[r0] = q0*L2E; fd[r1] = q1*L2E;
      atomicMax(gmax_u, __float_as_uint(q0*L2E + 64.0f));
      atomicMax(gmax_u, __float_as_uint(q1*L2E + 64.0f));
    }
    WhT[(size_t)l*NN + r0] = f2bf(acc0);
    WhT[(size_t)l*NN + r1] = f2bf(acc1);
  } else {
    const unsigned cid = (unsigned)(bid >> 1);          // 0..1023
    const iv4* __restrict__ base = (const iv4*)adj;     // 2M iv4s total
    // quarter-row s (0..32767): 2048 ints; wave wv covers groups 2wv,2wv+1.
    // iv4 offset of wave's first group: s*512 + wv*128 + l.
    const unsigned wvo = (unsigned)wv*128u + (unsigned)l;
    unsigned s0q = cid, s1q = cid + 1024u;
    iv4 d0 = base[s0q*512u + wvo], d1 = base[s0q*512u + wvo + 64u];
    iv4 e0 = base[s1q*512u + wvo], e1 = base[s1q*512u + wvo + 64u];
    #pragma unroll 1
    for (int it = 0; it < 32; ++it){
      const unsigned cur = cid + (unsigned)it*1024u;
      unsigned nx2 = cur + 2048u; if (nx2 > 32767u) nx2 = 32767u;  // clamp
      iv4 f0 = base[nx2*512u + wvo], f1 = base[nx2*512u + wvo + 64u];
      const unsigned row = cur >> 2, q = cur & 3u;
      unsigned* __restrict__ mp = mask + row*256u;
      const int g0 = (int)(q*8u) + 2*wv;
      cv_process(d0, l, mp, g0);
      cv_process(d1, l, mp, g0 + 1);
      d0 = e0; d1 = e1; e0 = f0; e1 = f1;
    }
  }
}

// ---- k_attn (R10/R12-verified, unchanged): block = 64 i-rows x 1024-j kchunk.
// WhT+fd staged in LDS; adj via bitmask (1 word / 32 j, L2-resident).
__device__ __forceinline__ void attn_math(unsigned mbits, f32x4 fv0, f32x4 fv1,
    short8 w0, short8 w1, short8 w2, short8 w3,
    float fsrL, float mL, f32x4* acc, float& s0, float& s1){
  const float fv[8] = {fv0[0],fv0[1],fv0[2],fv0[3], fv1[0],fv1[1],fv1[2],fv1[3]};
  float w[8];
  #pragma unroll
  for (int j = 0; j < 8; ++j){
    float x  = fsrL + fv[j];                      // log2 domain
    float tt = fmaxf(x, 0.2f*x);                  // leaky_relu (scale-invariant)
    float e  = __builtin_amdgcn_exp2f(tt - mL);   // v_exp_f32
    w[j] = (mbits & (1u << j)) ? e : 0.0f;        // adj bit
  }
  s0 += (w[0]+w[2]) + (w[4]+w[6]);
  s1 += (w[1]+w[3]) + (w[5]+w[7]);
  short8 af;
  __hip_bfloat162* afp = (__hip_bfloat162*)&af;
  #pragma unroll
  for (int j = 0; j < 4; ++j)
    afp[j] = __float22bfloat162_rn(make_float2(w[2*j], w[2*j+1]));  // v_cvt_pk_bf16_f32
  acc[0] = __builtin_amdgcn_mfma_f32_16x16x32_bf16(af, w0, acc[0], 0,0,0);
  acc[1] = __builtin_amdgcn_mfma_f32_16x16x32_bf16(af, w1, acc[1], 0,0,0);
  acc[2] = __builtin_amdgcn_mfma_f32_16x16x32_bf16(af, w2, acc[2], 0,0,0);
  acc[3] = __builtin_amdgcn_mfma_f32_16x16x32_bf16(af, w3, acc[3], 0,0,0);
}

// Verified layouts (m89/m120): A[m=lane&15][k=(lane>>4)*8+j],
// B[k=(lane>>4)*8+j][n=lane&15], C col=lane&15 row=(lane>>4)*4+reg.
__global__ __launch_bounds__(256, 4) void k_attn(const unsigned* __restrict__ mask,
    const unsigned short* __restrict__ WhT, const float* __restrict__ fs,
    const float* __restrict__ fd, const unsigned* __restrict__ gmax_u,
    float* __restrict__ acc_out, float* __restrict__ s_out){
  __shared__ unsigned short bslab[2][64*PADK];   // [buf][n][k]
  __shared__ float fslab[2][32];
  const int t = threadIdx.x, l = t & 63, wv = t >> 6;
  const int g = blockIdx.x & 127;        // 128 groups of 64 i-rows
  const int kchunk = blockIdx.x >> 7;    // 8 k-splits of 1024 j
  const int row = l & 15, quad = l >> 4;
  const int ibase = g*64 + wv*16;
  const int irow  = ibase + row;
  const float gmaxL = __uint_as_float(*gmax_u) - 64.0f;
  const float fsrL  = fs[irow];
  const float xL    = fsrL + gmaxL;
  const float mL    = fmaxf(xL, 0.2f*xL);  // row-max upper bound (leaky monotone)

  const unsigned jbase = (unsigned)kchunk*1024u;
  const unsigned m_off = (unsigned)irow*256u + (jbase >> 5);  // word per 32 j
  const unsigned sg_off = (unsigned)l*8192u + jbase + (unsigned)wv*8u;
  const int      sl_off = l*PADK + wv*8;
  const int      qsh    = quad*8;

  f32x4 acc[4];
  #pragma unroll
  for (int nb = 0; nb < 4; ++nb) acc[nb] = (f32x4){0.f,0.f,0.f,0.f};

  // prologue: stage step 0 into buf 0; prefetch mask words for steps 0,1
  {
    short8 v = *(const short8*)(WhT + sg_off);
    *(short8*)&bslab[0][sl_off] = v;
    if (t < 32) fslab[0][t] = fd[jbase + t];
  }
  unsigned m0 = mask[m_off + 0] >> qsh;
  unsigned m1 = mask[m_off + 1] >> qsh;

  float s0 = 0.f, s1 = 0.f;
  short8 nw; float nf = 0.f;

  #pragma unroll 1
  for (int s = 0; s < 32; s += 2){
    // ---- even sub-step: consume buf0/m0, stage s+1 -> buf1
    BAR();
    nw = *(const short8*)(WhT + sg_off + (s+1)*32);
    if (t < 32) nf = fd[jbase + (s+1)*32 + t];
    {
      f32x4 fv0 = *(const f32x4*)&fslab[0][qsh];
      f32x4 fv1 = *(const f32x4*)&fslab[0][qsh + 4];
      short8 w0 = *(const short8*)&bslab[0][( 0 + row)*PADK + qsh];
      short8 w1 = *(const short8*)&bslab[0][(16 + row)*PADK + qsh];
      short8 w2 = *(const short8*)&bslab[0][(32 + row)*PADK + qsh];
      short8 w3 = *(const short8*)&bslab[0][(48 + row)*PADK + qsh];
      attn_math(m0, fv0, fv1, w0, w1, w2, w3, fsrL, mL, acc, s0, s1);
    }
    if (s + 2 < 32) m0 = mask[m_off + s + 2] >> qsh;
    *(short8*)&bslab[1][sl_off] = nw;
    if (t < 32) fslab[1][t] = nf;

    // ---- odd sub-step: consume buf1/m1, stage s+2 -> buf0
    BAR();
    if (s + 2 < 32){
      nw = *(const short8*)(WhT + sg_off + (s+2)*32);
      if (t < 32) nf = fd[jbase + (s+2)*32 + t];
    }
    {
      f32x4 fv0 = *(const f32x4*)&fslab[1][qsh];
      f32x4 fv1 = *(const f32x4*)&fslab[1][qsh + 4];
      short8 w0 = *(const short8*)&bslab[1][( 0 + row)*PADK + qsh];
      short8 w1 = *(const short8*)&bslab[1][(16 + row)*PADK + qsh];
      short8 w2 = *(const short8*)&bslab[1][(32 + row)*PADK + qsh];
      short8 w3 = *(const short8*)&bslab[1][(48 + row)*PADK + qsh];
      attn_math(m1, fv0, fv1, w0, w1, w2, w3, fsrL, mL, acc, s0, s1);
    }
    if (s + 3 < 32) m1 = mask[m_off + s + 3] >> qsh;
    if (s + 2 < 32){
      *(short8*)&bslab[0][sl_off] = nw;
      if (t < 32) fslab[0][t] = nf;
    }
  }

  float sacc = s0 + s1;
  sacc += __shfl_xor(sacc, 16);
  sacc += __shfl_xor(sacc, 32);
  if (l < 16) s_out[kchunk*NN + ibase + l] = sacc;
  float* op = acc_out + ((size_t)kchunk*NN + ibase)*FOUT;
  #pragma unroll
  for (int nb = 0; nb < 4; ++nb)
    #pragma unroll
    for (int r = 0; r < 4; ++r)
      op[(quad*4 + r)*FOUT + nb*16 + row] = acc[nb][r];
}

// ---- k_out: combine 8 split-K partials, normalize, ELU.
__global__ __launch_bounds__(256) void k_out(const float* __restrict__ acc,
    const float* __restrict__ s, float* __restrict__ out){
  const int idx = blockIdx.x*256 + threadIdx.x;   // 524288 total
  const int i = idx >> 6;
  float num = 0.f, den = 0.f;
  #pragma unroll
  for (int ks = 0; ks < 8; ++ks){
    num += acc[idx + (size_t)ks*(NN*FOUT)];
    den += s[i + ks*NN];
  }
  float x = num / den;
  out[idx] = (x > 0.f) ? x : (__expf(x) - 1.0f);
}

extern "C" void kernel_launch(void* const* d_in, const int* in_sizes, int n_in,
                              void* d_out, int out_size, void* d_ws, size_t ws_size,
                              hipStream_t stream){
  const float* h   = (const float*)d_in[0];
  const int*   adj = (const int*)d_in[1];
  const float* W   = (const float*)d_in[2];
  const float* a   = (const float*)d_in[3];
  char* ws = (char*)d_ws;
  // ws: [0,1M) WhT | 1M fs | +32K fd | +64K gmax | [2M,18M) acc x8 |
  //     [20M,+256K) s x8 | [48M,56M) mask (2M words)
  unsigned short* WhT = (unsigned short*)ws;
  float*    fs     = (float*)(ws + (1u<<20));
  float*    fd     = (float*)(ws + (1u<<20) + 32768);
  unsigned* gmax_u = (unsigned*)(ws + (1u<<20) + 65536);
  float*    acc    = (float*)(ws + (2u<<20));
  float*    s_ws   = (float*)(ws + (20u<<20));
  unsigned* mask   = (unsigned*)(ws + (48u<<20));

  (void)hipMemsetAsync(gmax_u, 0, 4, stream);
  k_pm<<<2048, 256, 0, stream>>>(h, W, a, adj, WhT, fs, fd, gmax_u, mask);
  k_attn<<<1024, 256, 0, stream>>>(mask, WhT, fs, fd, gmax_u, acc, s_ws);
  k_out<<<2048, 256, 0, stream>>>(acc, s_ws, (float*)d_out);
}